// Round 12
// baseline (7850.665 us; speedup 1.0000x reference)
//
#include <hip/hip_runtime.h>
#include <hip/hip_bf16.h>
#include <cmath>

// ---------------- types & helpers ----------------
typedef __attribute__((ext_vector_type(8))) short short8;   // 8 bf16
typedef __attribute__((ext_vector_type(4))) float f32x4;
typedef __attribute__((ext_vector_type(4))) unsigned int u32x4;

union AFu { u32x4 v; short8 s; };

__device__ inline float bf2f(ushort u) {
    unsigned v = (unsigned)u << 16; float f; __builtin_memcpy(&f, &v, 4); return f;
}
__device__ inline ushort f2bf(float f) {
    __hip_bfloat16 h = __float2bfloat16(f); ushort u; __builtin_memcpy(&u, &h, 2); return u;
}
__device__ inline float sigf(float z) { return 1.f / (1.f + expf(-z)); }

// system-scope data movement — proven r6/r8/r11
__device__ __forceinline__ void sysst32(void* p, unsigned v) {
    __hip_atomic_store((unsigned*)p, v, __ATOMIC_RELAXED, __HIP_MEMORY_SCOPE_SYSTEM);
}

// 8 x 16B system-scope loads at base + {0,128,...,896}, ONE wait.
// Same proven primitive as r8's ld8_sys, stride 128 for the chunk layout.
__device__ __forceinline__ void ld8_s128(const void* base,
    u32x4& a0, u32x4& a1, u32x4& a2, u32x4& a3,
    u32x4& a4, u32x4& a5, u32x4& a6, u32x4& a7)
{
    asm volatile(
        "global_load_dwordx4 %0, %8, off sc0 sc1\n\t"
        "global_load_dwordx4 %1, %8, off offset:128 sc0 sc1\n\t"
        "global_load_dwordx4 %2, %8, off offset:256 sc0 sc1\n\t"
        "global_load_dwordx4 %3, %8, off offset:384 sc0 sc1\n\t"
        "global_load_dwordx4 %4, %8, off offset:512 sc0 sc1\n\t"
        "global_load_dwordx4 %5, %8, off offset:640 sc0 sc1\n\t"
        "global_load_dwordx4 %6, %8, off offset:768 sc0 sc1\n\t"
        "global_load_dwordx4 %7, %8, off offset:896 sc0 sc1\n\t"
        "s_waitcnt vmcnt(0)"
        : "=&v"(a0), "=&v"(a1), "=&v"(a2), "=&v"(a3),
          "=&v"(a4), "=&v"(a5), "=&v"(a6), "=&v"(a7)
        : "v"(base)
        : "memory");
}

// dims
#define BB 256
#define LL 256
#define HH 512
#define G4 2048

// XOR swizzle for 1024-B LDS rows (proven r4-r11)
__device__ __forceinline__ unsigned swz(unsigned row, unsigned byteInRow) {
    return (row * 1024u + byteInRow) ^ ((row & 7u) << 4);
}

// Epoch-slot barrier, split arrive/wait (r11, proven).
__device__ __forceinline__ void rb_arrive(unsigned* slots, int sub, unsigned epoch) {
    asm volatile("s_waitcnt vmcnt(0)" ::: "memory");   // my system stores done
    __syncthreads();                                   // all waves done
    if (threadIdx.x == 0)
        __hip_atomic_store(slots + sub, epoch, __ATOMIC_RELAXED, __HIP_MEMORY_SCOPE_AGENT);
}
__device__ __forceinline__ void rb_wait(unsigned* slots, unsigned epoch) {
    if (threadIdx.x < 16)
        while (__hip_atomic_load(slots + threadIdx.x, __ATOMIC_RELAXED,
                                 __HIP_MEMORY_SCOPE_AGENT) < epoch)
            __builtin_amdgcn_s_sleep(1);
    __syncthreads();
}

// ---------------- prologue kernels (proven rounds 3-11) ----------------

__global__ __launch_bounds__(256) void init_state(ushort* hp) {
    int i = blockIdx.x * 256 + threadIdx.x;
    hp[i] = 0;
}

__global__ __launch_bounds__(256) void transpose_f32_bf16(
    const float* __restrict__ in, ushort* __restrict__ out, int K, int N)
{
    __shared__ float tile[32][33];
    int tx = threadIdx.x & 31, ty = threadIdx.x >> 5;
    int bk = blockIdx.x * 32, bn = blockIdx.y * 32;
    #pragma unroll
    for (int i = 0; i < 32; i += 8)
        tile[ty + i][tx] = in[(size_t)(bk + ty + i) * N + (bn + tx)];
    __syncthreads();
    #pragma unroll
    for (int i = 0; i < 32; i += 8)
        out[(size_t)(bn + ty + i) * K + (bk + tx)] = f2bf(tile[tx][ty + i]);
}

__global__ __launch_bounds__(256) void combine_w(
    const float* __restrict__ base, const float* __restrict__ A,
    const float* __restrict__ Bm, float* __restrict__ out, int use_base)
{
    int n  = blockIdx.x * 256 + threadIdx.x;
    int k0 = blockIdx.y * 8;
    float acc[8];
    #pragma unroll
    for (int r = 0; r < 8; ++r)
        acc[r] = use_base ? base[(size_t)(k0 + r) * G4 + n] : 0.f;
    for (int m = 0; m < 512; ++m) {
        float bv = Bm[(size_t)m * G4 + n];
        #pragma unroll
        for (int r = 0; r < 8; ++r)
            acc[r] = fmaf(A[(size_t)(k0 + r) * 512 + m], bv, acc[r]);
    }
    #pragma unroll
    for (int r = 0; r < 8; ++r) out[(size_t)(k0 + r) * G4 + n] = acc[r];
}

__global__ __launch_bounds__(256) void bias_g_kernel(
    const float* __restrict__ Wih_b, const float* __restrict__ Whm_b,
    const float* __restrict__ Wmx_b, const float* __restrict__ Wmh_b,
    const float* __restrict__ Whm, float* __restrict__ bias_g)
{
    int n = blockIdx.x * 256 + threadIdx.x;
    float acc = Wih_b[n] + Whm_b[n];
    for (int m = 0; m < 512; ++m)
        acc = fmaf(Wmx_b[m] + Wmh_b[m], Whm[(size_t)m * G4 + n], acc);
    bias_g[n] = acc;
}

// ---------------- persistent fused kernel ----------------
// 256 WGs x 256 thr, 1 WG/CU (84KB LDS forces it). WG = (rb = blockIdx>>4:
// 16 batch rows, cs = blockIdx&15: 32 cols). Transport/barrier = r8/r11.
// NEW: chunk-direct A-path — wave (kp = K-chunk parity, ct = col-tile); each
// lane's 8 A-frags load straight from global (ld8_s128) into MFMA, no LDS
// staging. S6 in the same layout: W2 partials reuse S5's in-reg h2 frags.

__device__ __forceinline__ void mog2(
    const ushort* __restrict__ Ag, const ushort* Wlds,
    ushort (*myBuf)[32], ushort* __restrict__ outG,
    const float* __restrict__ xscale, float (*pbuf)[16][16],
    int r0, int cs, int t, int tid,
    u32x4& a0, u32x4& a1, u32x4& a2, u32x4& a3,
    u32x4& a4, u32x4& a5, u32x4& a6, u32x4& a7)
{
    int lane = tid & 63, wave = tid >> 6;
    int lr = lane & 15, lk = lane >> 4;
    int kp = wave >> 1, ct = wave & 1;
    int colloc = ct * 16 + lr;

    float xs[4];
    if (xscale != nullptr && kp == 0) {
        #pragma unroll
        for (int r = 0; r < 4; ++r)
            xs[r] = xscale[((size_t)(r0 + lk * 4 + r) * LL + t) * HH + cs * 32 + colloc];
    }

    // chunks j = 2i+kp: lane holds A[r0+lr][j*32 + lk*8 .. +8]
    const char* Ab = (const char*)(Ag + (size_t)(r0 + lr) * HH) + kp * 64 + lk * 16;
    ld8_s128(Ab, a0, a1, a2, a3, a4, a5, a6, a7);

    f32x4 acc = {0.f, 0.f, 0.f, 0.f};
#define MOGMF(i, ai) { AFu u; u.v = ai;                                          \
        short8 b = *(const short8*)((const char*)Wlds +                          \
            swz((unsigned)colloc, (unsigned)((2 * i + kp) * 64 + lk * 16)));     \
        acc = __builtin_amdgcn_mfma_f32_16x16x32_bf16(u.s, b, acc, 0, 0, 0); }
    MOGMF(0, a0) MOGMF(1, a1) MOGMF(2, a2) MOGMF(3, a3)
    MOGMF(4, a4) MOGMF(5, a5) MOGMF(6, a6) MOGMF(7, a7)
#undef MOGMF

    if (kp == 1) {
        #pragma unroll
        for (int r = 0; r < 4; ++r) pbuf[ct][lk * 4 + r][lr] = acc[r];
    }
    __syncthreads();
    if (kp == 0) {
        #pragma unroll
        for (int r = 0; r < 4; ++r) {
            float v = acc[r] + pbuf[ct][lk * 4 + r][lr];
            float sc = (xscale != nullptr) ? xs[r] : bf2f(myBuf[lk * 4 + r][colloc]);
            myBuf[lk * 4 + r][colloc] = f2bf(2.f * sigf(v) * sc);  // C/D: col=lane&15, row=(lane>>4)*4+r
        }
    }
    __syncthreads();
    {   // publish my 1 KB tile (256 x u32 system stores — r8/r11 proven path)
        int row = tid >> 4, c2 = tid & 15;
        unsigned v = *(const unsigned*)&myBuf[row][c2 * 2];
        sysst32((char*)outG + (((size_t)(r0 + row)) * HH + cs * 32 + c2 * 2) * 2, v);
    }
}

__global__ __launch_bounds__(256) void moglstm_persistent(
    const float* __restrict__ x,
    const ushort* __restrict__ QT, const ushort* __restrict__ RT,
    const ushort* __restrict__ W1T, const ushort* __restrict__ W2T,
    const float* __restrict__ biasg,
    ushort* __restrict__ hp, ushort* __restrict__ xa, ushort* __restrict__ hb1,
    ushort* __restrict__ xb, ushort* __restrict__ hb2, ushort* __restrict__ xc,
    float* __restrict__ out, unsigned* __restrict__ flags)
{
    __shared__ ushort QTs[32 * 512];      // 32 KB swizzled [local col][K]
    __shared__ ushort RTs[32 * 512];      // 32 KB
    __shared__ float  pbuf[2][16][16];    // 2 KB
    __shared__ ushort myX[16][32];        // 1 KB
    __shared__ ushort myH[16][32];        // 1 KB
    __shared__ float  gbuf[4][16][32];    // 8 KB
    __shared__ ushort padl[4096];         // pad -> 84 KB -> exactly 1 WG/CU

    int tid = threadIdx.x;
    asm volatile("" :: "v"((unsigned)(size_t)&padl[0]));   // keep padl allocated

    int rb = blockIdx.x >> 4, cs = blockIdx.x & 15;
    int r0 = rb * 16;
    int lane = tid & 63, wave = tid >> 6;
    int lr = lane & 15, lk = lane >> 4;
    int kp = wave >> 1, ct = wave & 1;
    int colloc = ct * 16 + lr;

    // Q/R weight slices -> LDS once (plain cached loads; read-only)
    #pragma unroll
    for (int i = 0; i < 8; ++i) {
        int ch = i * 256 + tid, col = ch >> 6, kc = ch & 63;
        *(u32x4*)((char*)QTs + swz((unsigned)col, (unsigned)(kc * 16))) =
            *(const u32x4*)(QT + (size_t)(cs * 32 + col) * HH + kc * 8);
        *(u32x4*)((char*)RTs + swz((unsigned)col, (unsigned)(kc * 16))) =
            *(const u32x4*)(RT + (size_t)(cs * 32 + col) * HH + kc * 8);
    }
    ((unsigned*)myH)[tid] = 0;            // h0 = 0
    float Creg[4] = {0.f, 0.f, 0.f, 0.f}; // cell state: kp0 lanes, 4 rows x 1 col
    __syncthreads();

    unsigned* slots = flags + rb * 16;    // 16 u32 per row-group
    u32x4 a0, a1, a2, a3, a4, a5, a6, a7;

    for (int t = 0; t < LL; ++t) {
        unsigned ep = (unsigned)t * 6u;
        // S1: x1 = 2*sig(h0 @ Q) * x_t
        mog2(hp, QTs, myX, xa, x, pbuf, r0, cs, t, tid, a0, a1, a2, a3, a4, a5, a6, a7);
        rb_arrive(slots, cs, ep + 1); rb_wait(slots, ep + 1);
        // S2: h1 = 2*sig(x1 @ R) * h0
        mog2(xa, RTs, myH, hb1, nullptr, pbuf, r0, cs, t, tid, a0, a1, a2, a3, a4, a5, a6, a7);
        rb_arrive(slots, cs, ep + 2); rb_wait(slots, ep + 2);
        // S3: x2 = 2*sig(h1 @ Q) * x1
        mog2(hb1, QTs, myX, xb, nullptr, pbuf, r0, cs, t, tid, a0, a1, a2, a3, a4, a5, a6, a7);
        rb_arrive(slots, cs, ep + 3); rb_wait(slots, ep + 3);
        // S4: h2 = 2*sig(x2 @ R) * h1
        mog2(xb, RTs, myH, hb2, nullptr, pbuf, r0, cs, t, tid, a0, a1, a2, a3, a4, a5, a6, a7);
        rb_arrive(slots, cs, ep + 4); rb_wait(slots, ep + 4);
        // S5: x3 = 2*sig(h2 @ Q) * x2 — a0..a7 = h2 chunks, kept live for W2
        mog2(hb2, QTs, myX, xc, nullptr, pbuf, r0, cs, t, tid, a0, a1, a2, a3, a4, a5, a6, a7);
        rb_arrive(slots, cs, ep + 5);

        // --- W2 gate partials during S5's wait window (h2 frags in regs) ---
        f32x4 g0 = {0,0,0,0}, g1 = {0,0,0,0}, g2 = {0,0,0,0}, g3 = {0,0,0,0};
#define GQ(gq, q, Wt) {                                                           \
        const short8* Bq = (const short8*)(Wt + (size_t)(q * 512 + cs * 32 + colloc) * HH); \
        AFu u;                                                                    \
        u.v = a0; gq = __builtin_amdgcn_mfma_f32_16x16x32_bf16(u.s, Bq[(0*2+kp)*4+lk], gq, 0,0,0); \
        u.v = a1; gq = __builtin_amdgcn_mfma_f32_16x16x32_bf16(u.s, Bq[(1*2+kp)*4+lk], gq, 0,0,0); \
        u.v = a2; gq = __builtin_amdgcn_mfma_f32_16x16x32_bf16(u.s, Bq[(2*2+kp)*4+lk], gq, 0,0,0); \
        u.v = a3; gq = __builtin_amdgcn_mfma_f32_16x16x32_bf16(u.s, Bq[(3*2+kp)*4+lk], gq, 0,0,0); \
        u.v = a4; gq = __builtin_amdgcn_mfma_f32_16x16x32_bf16(u.s, Bq[(4*2+kp)*4+lk], gq, 0,0,0); \
        u.v = a5; gq = __builtin_amdgcn_mfma_f32_16x16x32_bf16(u.s, Bq[(5*2+kp)*4+lk], gq, 0,0,0); \
        u.v = a6; gq = __builtin_amdgcn_mfma_f32_16x16x32_bf16(u.s, Bq[(6*2+kp)*4+lk], gq, 0,0,0); \
        u.v = a7; gq = __builtin_amdgcn_mfma_f32_16x16x32_bf16(u.s, Bq[(7*2+kp)*4+lk], gq, 0,0,0); }
        GQ(g0, 0, W2T) GQ(g1, 1, W2T) GQ(g2, 2, W2T) GQ(g3, 3, W2T)
        rb_wait(slots, ep + 5);           // x3 now published by all peers

        // --- W1 with x3 chunks (chunk-direct load) ---
        ld8_s128((const char*)(xc + (size_t)(r0 + lr) * HH) + kp * 64 + lk * 16,
                 a0, a1, a2, a3, a4, a5, a6, a7);
        GQ(g0, 0, W1T) GQ(g1, 1, W1T) GQ(g2, 2, W1T) GQ(g3, 3, W1T)
#undef GQ

        // reduce kp halves via gbuf
        if (kp == 1) {
            #pragma unroll
            for (int r = 0; r < 4; ++r) {
                gbuf[0][lk * 4 + r][colloc] = g0[r];
                gbuf[1][lk * 4 + r][colloc] = g1[r];
                gbuf[2][lk * 4 + r][colloc] = g2[r];
                gbuf[3][lk * 4 + r][colloc] = g3[r];
            }
        }
        __syncthreads();
        if (kp == 0) {
            float b0 = biasg[0 * 512 + cs * 32 + colloc];
            float b1 = biasg[1 * 512 + cs * 32 + colloc];
            float b2 = biasg[2 * 512 + cs * 32 + colloc];
            float b3 = biasg[3 * 512 + cs * 32 + colloc];
            #pragma unroll
            for (int r = 0; r < 4; ++r) {
                int row = lk * 4 + r;
                float gi = sigf(g0[r] + gbuf[0][row][colloc] + b0);
                float gf = sigf(g1[r] + gbuf[1][row][colloc] + b1);
                float gc = tanhf(g2[r] + gbuf[2][row][colloc] + b2);
                float go = sigf(g3[r] + gbuf[3][row][colloc] + b3);
                Creg[r] = gf * Creg[r] + gi * gc;
                float h = go * tanhf(Creg[r]);
                out[((size_t)(r0 + row) * LL + t) * HH + cs * 32 + colloc] = h;  // (B,L,H)
                myH[row][colloc] = f2bf(h);
            }
        }
        __syncthreads();
        {   // publish h_t -> hp (256 x u32 system stores)
            int row = tid >> 4, c2 = tid & 15;
            unsigned v = *(const unsigned*)&myH[row][c2 * 2];
            sysst32((char*)hp + (((size_t)(r0 + row)) * HH + cs * 32 + c2 * 2) * 2, v);
        }
        rb_arrive(slots, cs, ep + 6); rb_wait(slots, ep + 6);
    }
}

// ---------------- host launcher ----------------
extern "C" void kernel_launch(void* const* d_in, const int* in_sizes, int n_in,
                              void* d_out, int out_size, void* d_ws, size_t ws_size,
                              hipStream_t stream)
{
    const float* x     = (const float*)d_in[0];   // (256,256,512)
    const float* Wih_w = (const float*)d_in[1];   // (512,2048)
    const float* Wih_b = (const float*)d_in[2];   // (2048)
    const float* Wmx_w = (const float*)d_in[3];   // (512,512)
    const float* Wmx_b = (const float*)d_in[4];   // (512)
    const float* Wmh_w = (const float*)d_in[5];   // (512,512)
    const float* Wmh_b = (const float*)d_in[6];   // (512)
    const float* Whm_w = (const float*)d_in[7];   // (512,2048)
    const float* Whm_b = (const float*)d_in[8];   // (2048)
    const float* Q     = (const float*)d_in[9];   // (512,512)
    const float* R     = (const float*)d_in[10];  // (512,512)
    float* out = (float*)d_out;                   // (256,256,512)

    char* ws = (char*)d_ws;
    ushort* QT   = (ushort*)ws;               ws += (size_t)512 * 512 * 2;   // bf16 [outcol][K]
    ushort* RT   = (ushort*)ws;               ws += (size_t)512 * 512 * 2;
    ushort* W1T  = (ushort*)ws;               ws += (size_t)G4  * 512 * 2;
    ushort* W2T  = (ushort*)ws;               ws += (size_t)G4  * 512 * 2;
    float*  biasg= (float*)ws;                ws += (size_t)G4 * 4;
    ushort* xa   = (ushort*)ws;               ws += (size_t)BB * HH * 2;
    ushort* hb1  = (ushort*)ws;               ws += (size_t)BB * HH * 2;
    ushort* xb   = (ushort*)ws;               ws += (size_t)BB * HH * 2;
    ushort* hb2  = (ushort*)ws;               ws += (size_t)BB * HH * 2;
    ushort* xc   = (ushort*)ws;               ws += (size_t)BB * HH * 2;
    ushort* hp   = (ushort*)ws;               ws += (size_t)BB * HH * 2;
    float*  Wtmp = (float*)ws;                ws += (size_t)512 * G4 * 4;    // prologue-only

    // Epoch slots alias post-prologue-dead Wtmp: 16 rb x 16 slots u32 = 1 KB.
    unsigned* flags = (unsigned*)Wtmp;

    // prologue: state init + weight prep
    init_state<<<512, 256, 0, stream>>>(hp);
    transpose_f32_bf16<<<dim3(16, 16), 256, 0, stream>>>(Q, QT, 512, 512);
    transpose_f32_bf16<<<dim3(16, 16), 256, 0, stream>>>(R, RT, 512, 512);
    combine_w<<<dim3(8, 64), 256, 0, stream>>>(Wih_w, Wmx_w, Whm_w, Wtmp, 1);   // W1 = Wih + Wmx@Whm
    transpose_f32_bf16<<<dim3(16, 64), 256, 0, stream>>>(Wtmp, W1T, 512, G4);
    combine_w<<<dim3(8, 64), 256, 0, stream>>>(nullptr, Wmh_w, Whm_w, Wtmp, 0); // W2 = Wmh@Whm
    transpose_f32_bf16<<<dim3(16, 64), 256, 0, stream>>>(Wtmp, W2T, 512, G4);
    bias_g_kernel<<<8, 256, 0, stream>>>(Wih_b, Whm_b, Wmx_b, Wmh_b, Whm_w, biasg);
    hipMemsetAsync(flags, 0, (size_t)16 * 16 * sizeof(unsigned), stream);

    // one persistent kernel for the entire sequence
    moglstm_persistent<<<256, 256, 0, stream>>>(x, QT, RT, W1T, W2T, biasg,
                                                hp, xa, hb1, xb, hb2, xc, out, flags);
}

// Round 13
// 7242.386 us; speedup vs baseline: 1.0840x; 1.0840x over previous
//
#include <hip/hip_runtime.h>
#include <hip/hip_bf16.h>
#include <cmath>

// ---------------- types & helpers ----------------
typedef __attribute__((ext_vector_type(8))) short short8;   // 8 bf16
typedef __attribute__((ext_vector_type(4))) float f32x4;
typedef __attribute__((ext_vector_type(2))) float f32x2;
typedef __attribute__((ext_vector_type(4))) unsigned int u32x4;

__device__ inline float bf2f(ushort u) {
    unsigned v = (unsigned)u << 16; float f; __builtin_memcpy(&f, &v, 4); return f;
}
__device__ inline ushort f2bf(float f) {
    __hip_bfloat16 h = __float2bfloat16(f); ushort u; __builtin_memcpy(&u, &h, 2); return u;
}
__device__ inline float sigf(float z) { return 1.f / (1.f + expf(-z)); }

// AGENT-scope publish (r13 change: was SYSTEM in r11). Same scope as the
// proven flag stores -> visible device-wide, but coherence point = L3, not
// HBM: shorter drain at rb_arrive. Consumers read with sc0 sc1 (hits L3).
__device__ __forceinline__ void agst32(void* p, unsigned v) {
    __hip_atomic_store((unsigned*)p, v, __ATOMIC_RELAXED, __HIP_MEMORY_SCOPE_AGENT);
}

// dims
#define BB 256
#define LL 256
#define HH 512
#define G4 2048

// XOR swizzle for 1024-B LDS rows (proven r4-r12)
__device__ __forceinline__ unsigned swz(unsigned row, unsigned byteInRow) {
    return (row * 1024u + byteInRow) ^ ((row & 7u) << 4);
}

// Cooperative A-tile stage (r11, proven): 16 rows x 512 cols bf16 from global
// (device-coherent load: sc0 sc1, served from L3) into swizzled LDS.
// 256 thr x 64 contiguous bytes: fully coalesced.
__device__ __forceinline__ void stage_A16(const ushort* Ag, int r0, ushort* Ast, int tid) {
    const char* src = (const char*)(Ag + (size_t)(r0 + (tid >> 4)) * HH + (tid & 15) * 32);
    u32x4 v0, v1, v2, v3;
    asm volatile(
        "global_load_dwordx4 %0, %4, off sc0 sc1\n\t"
        "global_load_dwordx4 %1, %4, off offset:16 sc0 sc1\n\t"
        "global_load_dwordx4 %2, %4, off offset:32 sc0 sc1\n\t"
        "global_load_dwordx4 %3, %4, off offset:48 sc0 sc1\n\t"
        "s_waitcnt vmcnt(0)"
        : "=&v"(v0), "=&v"(v1), "=&v"(v2), "=&v"(v3) : "v"(src) : "memory");
    unsigned row = (unsigned)(tid >> 4), b = (unsigned)((tid & 15) * 64);
    *(u32x4*)((char*)Ast + swz(row, b))      = v0;
    *(u32x4*)((char*)Ast + swz(row, b + 16)) = v1;
    *(u32x4*)((char*)Ast + swz(row, b + 32)) = v2;
    *(u32x4*)((char*)Ast + swz(row, b + 48)) = v3;
}

// Epoch-slot barrier, split arrive/wait (r11, proven).
__device__ __forceinline__ void rb_arrive(unsigned* slots, int sub, unsigned epoch) {
    asm volatile("s_waitcnt vmcnt(0)" ::: "memory");   // my publish stores done
    __syncthreads();                                   // all waves done
    if (threadIdx.x == 0)
        __hip_atomic_store(slots + sub, epoch, __ATOMIC_RELAXED, __HIP_MEMORY_SCOPE_AGENT);
}
__device__ __forceinline__ void rb_wait(unsigned* slots, unsigned epoch) {
    if (threadIdx.x < 16)
        while (__hip_atomic_load(slots + threadIdx.x, __ATOMIC_RELAXED,
                                 __HIP_MEMORY_SCOPE_AGENT) < epoch)
            __builtin_amdgcn_s_sleep(1);
    __syncthreads();
}

// ---------------- prologue kernels (proven rounds 3-12) ----------------

__global__ __launch_bounds__(256) void init_state(ushort* hp) {
    int i = blockIdx.x * 256 + threadIdx.x;
    hp[i] = 0;
}

__global__ __launch_bounds__(256) void transpose_f32_bf16(
    const float* __restrict__ in, ushort* __restrict__ out, int K, int N)
{
    __shared__ float tile[32][33];
    int tx = threadIdx.x & 31, ty = threadIdx.x >> 5;
    int bk = blockIdx.x * 32, bn = blockIdx.y * 32;
    #pragma unroll
    for (int i = 0; i < 32; i += 8)
        tile[ty + i][tx] = in[(size_t)(bk + ty + i) * N + (bn + tx)];
    __syncthreads();
    #pragma unroll
    for (int i = 0; i < 32; i += 8)
        out[(size_t)(bn + ty + i) * K + (bk + tx)] = f2bf(tile[tx][ty + i]);
}

__global__ __launch_bounds__(256) void combine_w(
    const float* __restrict__ base, const float* __restrict__ A,
    const float* __restrict__ Bm, float* __restrict__ out, int use_base)
{
    int n  = blockIdx.x * 256 + threadIdx.x;
    int k0 = blockIdx.y * 8;
    float acc[8];
    #pragma unroll
    for (int r = 0; r < 8; ++r)
        acc[r] = use_base ? base[(size_t)(k0 + r) * G4 + n] : 0.f;
    for (int m = 0; m < 512; ++m) {
        float bv = Bm[(size_t)m * G4 + n];
        #pragma unroll
        for (int r = 0; r < 8; ++r)
            acc[r] = fmaf(A[(size_t)(k0 + r) * 512 + m], bv, acc[r]);
    }
    #pragma unroll
    for (int r = 0; r < 8; ++r) out[(size_t)(k0 + r) * G4 + n] = acc[r];
}

__global__ __launch_bounds__(256) void bias_g_kernel(
    const float* __restrict__ Wih_b, const float* __restrict__ Whm_b,
    const float* __restrict__ Wmx_b, const float* __restrict__ Wmh_b,
    const float* __restrict__ Whm, float* __restrict__ bias_g)
{
    int n = blockIdx.x * 256 + threadIdx.x;
    float acc = Wih_b[n] + Whm_b[n];
    for (int m = 0; m < 512; ++m)
        acc = fmaf(Wmx_b[m] + Wmh_b[m], Whm[(size_t)m * G4 + n], acc);
    bias_g[n] = acc;
}

// ---------------- persistent fused kernel ----------------
// 256 WGs x 256 thr, 1 WG/CU (92KB LDS). WG = (rb = blockIdx>>4: 16 batch
// rows, cs = blockIdx&15: 32 cols). Structure = r11 (best). r13 change:
// activation publishes at AGENT scope (land in L3, not HBM).

__device__ __forceinline__ void mog_stage_p(
    const ushort* Ast,            // staged A-tile (16 x 512 bf16, swizzled)
    const ushort* Wlds,
    ushort (*myBuf)[32], ushort* __restrict__ outG,
    const float* __restrict__ xscale, float (*pbuf)[16][16],
    int r0, int cs, int t, int tid)
{
    int lane = tid & 63, wave = tid >> 6;
    int lr = lane & 15, lk = lane >> 4;
    int ct = wave & 1, kh = wave >> 1;
    int colloc = ct * 16 + lr;

    float xs[4];
    if (xscale != nullptr && kh == 0) {
        #pragma unroll
        for (int r = 0; r < 4; ++r)
            xs[r] = xscale[((size_t)(r0 + lk * 4 + r) * LL + t) * HH + cs * 32 + colloc];
    }

    f32x4 acc = {0.f, 0.f, 0.f, 0.f};
    #pragma unroll
    for (int kk = 0; kk < 8; ++kk) {
        short8 a = *(const short8*)((const char*)Ast +
                     swz((unsigned)lr, (unsigned)(kh * 512 + kk * 64 + lk * 16)));
        short8 b = *(const short8*)((const char*)Wlds +
                     swz((unsigned)colloc, (unsigned)(kh * 512 + kk * 64 + lk * 16)));
        acc = __builtin_amdgcn_mfma_f32_16x16x32_bf16(a, b, acc, 0, 0, 0);
    }

    if (kh == 1) {
        #pragma unroll
        for (int r = 0; r < 4; ++r) pbuf[ct][lk * 4 + r][lr] = acc[r];
    }
    __syncthreads();
    if (kh == 0) {
        #pragma unroll
        for (int r = 0; r < 4; ++r) {
            float v = acc[r] + pbuf[ct][lk * 4 + r][lr];
            float sc = (xscale != nullptr) ? xs[r] : bf2f(myBuf[lk * 4 + r][colloc]);
            myBuf[lk * 4 + r][colloc] = f2bf(2.f * sigf(v) * sc);  // C/D: col=lane&15, row=(lane>>4)*4+r
        }
    }
    __syncthreads();
    {   // publish my 1 KB tile (coalesced u32 AGENT stores — r13 change)
        int row = tid >> 4, c2 = tid & 15;
        unsigned v = *(const unsigned*)&myBuf[row][c2 * 2];
        agst32((char*)outG + (((size_t)(r0 + row)) * HH + cs * 32 + c2 * 2) * 2, v);
    }
}

__global__ __launch_bounds__(256) void moglstm_persistent(
    const float* __restrict__ x,
    const ushort* __restrict__ QT, const ushort* __restrict__ RT,
    const ushort* __restrict__ W1T, const ushort* __restrict__ W2T,
    const float* __restrict__ biasg,
    ushort* __restrict__ hp, ushort* __restrict__ xa, ushort* __restrict__ hb1,
    ushort* __restrict__ xb, ushort* __restrict__ hb2, ushort* __restrict__ xc,
    float* __restrict__ out, unsigned* __restrict__ flags)
{
    __shared__ ushort QTs[32 * 512];      // 32 KB swizzled [local col][K]
    __shared__ ushort RTs[32 * 512];      // 32 KB
    __shared__ ushort Ast[16 * 512];      // 16 KB staged A-tile (swizzled)
    __shared__ float  pbuf[2][16][16];    // 2 KB
    __shared__ ushort myX[16][32];        // 1 KB
    __shared__ ushort myH[16][32];        // 1 KB
    __shared__ float  gbuf[4][16][32];    // 8 KB   -> ~92 KB -> 1 WG/CU

    int tid = threadIdx.x;
    int rb = blockIdx.x >> 4, cs = blockIdx.x & 15;
    int r0 = rb * 16;
    int lane = tid & 63, wave = tid >> 6;
    int lr = lane & 15, lk = lane >> 4;

    // Q/R weight slices -> LDS once (plain cached loads; read-only)
    #pragma unroll
    for (int i = 0; i < 8; ++i) {
        int ch = i * 256 + tid, col = ch >> 6, kc = ch & 63;
        *(u32x4*)((char*)QTs + swz((unsigned)col, (unsigned)(kc * 16))) =
            *(const u32x4*)(QT + (size_t)(cs * 32 + col) * HH + kc * 8);
        *(u32x4*)((char*)RTs + swz((unsigned)col, (unsigned)(kc * 16))) =
            *(const u32x4*)(RT + (size_t)(cs * 32 + col) * HH + kc * 8);
    }
    ((unsigned*)myH)[tid] = 0;            // h0 = 0
    float Creg0 = 0.f, Creg1 = 0.f;       // cell state lives in VGPRs all run
    __syncthreads();

    unsigned* slots = flags + rb * 16;    // 16 u32 per row-group

    for (int t = 0; t < LL; ++t) {
        unsigned ep = (unsigned)t * 6u;

        // S1: x1 = 2*sig(h0 @ Q) * x_t
        stage_A16(hp, r0, Ast, tid); __syncthreads();
        mog_stage_p(Ast, QTs, myX, xa, x, pbuf, r0, cs, t, tid);
        rb_arrive(slots, cs, ep + 1); rb_wait(slots, ep + 1);
        // S2: h1 = 2*sig(x1 @ R) * h0
        stage_A16(xa, r0, Ast, tid); __syncthreads();
        mog_stage_p(Ast, RTs, myH, hb1, nullptr, pbuf, r0, cs, t, tid);
        rb_arrive(slots, cs, ep + 2); rb_wait(slots, ep + 2);
        // S3: x2 = 2*sig(h1 @ Q) * x1
        stage_A16(hb1, r0, Ast, tid); __syncthreads();
        mog_stage_p(Ast, QTs, myX, xb, nullptr, pbuf, r0, cs, t, tid);
        rb_arrive(slots, cs, ep + 3); rb_wait(slots, ep + 3);
        // S4: h2 = 2*sig(x2 @ R) * h1
        stage_A16(xb, r0, Ast, tid); __syncthreads();
        mog_stage_p(Ast, RTs, myH, hb2, nullptr, pbuf, r0, cs, t, tid);
        rb_arrive(slots, cs, ep + 4); rb_wait(slots, ep + 4);

        // S5: x3 = 2*sig(h2 @ Q) * x2   — A-tile (h2) staged once, shared with W2
        stage_A16(hb2, r0, Ast, tid); __syncthreads();
        mog_stage_p(Ast, QTs, myX, xc, nullptr, pbuf, r0, cs, t, tid);
        rb_arrive(slots, cs, ep + 5);

        // --- inside S5's wait window: gate partial h2 @ W2 (Ast still = h2) ---
        int q = wave;
        f32x4 acc0 = {0,0,0,0}, acc1 = {0,0,0,0};
        {
            const short8* B0 = (const short8*)(W2T + (size_t)(q * 512 + cs * 32 + lr) * HH);
            const short8* B1 = (const short8*)(W2T + (size_t)(q * 512 + cs * 32 + 16 + lr) * HH);
            #pragma unroll
            for (int kk = 0; kk < 16; ++kk) {
                short8 a = *(const short8*)((const char*)Ast +
                             swz((unsigned)lr, (unsigned)(kk * 64 + lk * 16)));
                acc0 = __builtin_amdgcn_mfma_f32_16x16x32_bf16(a, B0[kk * 4 + lk], acc0, 0, 0, 0);
                acc1 = __builtin_amdgcn_mfma_f32_16x16x32_bf16(a, B1[kk * 4 + lk], acc1, 0, 0, 0);
            }
        }
        rb_wait(slots, ep + 5);           // x3 now published by all peers

        // S6: gates += x3 @ W1; bias; LSTM cell
        stage_A16(xc, r0, Ast, tid); __syncthreads();
        {
            const short8* B0 = (const short8*)(W1T + (size_t)(q * 512 + cs * 32 + lr) * HH);
            const short8* B1 = (const short8*)(W1T + (size_t)(q * 512 + cs * 32 + 16 + lr) * HH);
            #pragma unroll
            for (int kk = 0; kk < 16; ++kk) {
                short8 a = *(const short8*)((const char*)Ast +
                             swz((unsigned)lr, (unsigned)(kk * 64 + lk * 16)));
                acc0 = __builtin_amdgcn_mfma_f32_16x16x32_bf16(a, B0[kk * 4 + lk], acc0, 0, 0, 0);
                acc1 = __builtin_amdgcn_mfma_f32_16x16x32_bf16(a, B1[kk * 4 + lk], acc1, 0, 0, 0);
            }
        }
        {
            float b0 = biasg[q * 512 + cs * 32 + lr];
            float b1 = biasg[q * 512 + cs * 32 + 16 + lr];
            #pragma unroll
            for (int r = 0; r < 4; ++r) {
                gbuf[q][lk * 4 + r][lr]      = acc0[r] + b0;
                gbuf[q][lk * 4 + r][16 + lr] = acc1[r] + b1;
            }
        }
        __syncthreads();
        {   // cell: thread owns (row=tid>>4, cols 2*(tid&15)+{0,1}) forever
            int row = tid >> 4, c2 = tid & 15;
            int colg = cs * 32 + c2 * 2;
            float i0 = sigf(gbuf[0][row][c2 * 2]),      f0 = sigf(gbuf[1][row][c2 * 2]);
            float g0 = tanhf(gbuf[2][row][c2 * 2]),     o0 = sigf(gbuf[3][row][c2 * 2]);
            Creg0 = f0 * Creg0 + i0 * g0;
            float h0v = o0 * tanhf(Creg0);
            float i1 = sigf(gbuf[0][row][c2 * 2 + 1]),  f1 = sigf(gbuf[1][row][c2 * 2 + 1]);
            float g1 = tanhf(gbuf[2][row][c2 * 2 + 1]), o1 = sigf(gbuf[3][row][c2 * 2 + 1]);
            Creg1 = f1 * Creg1 + i1 * g1;
            float h1v = o1 * tanhf(Creg1);
            f32x2 hv2 = {h0v, h1v};
            *(f32x2*)(out + ((size_t)(r0 + row) * LL + t) * HH + colg) = hv2;  // (B,L,H)
            unsigned hu = (unsigned)f2bf(h0v) | ((unsigned)f2bf(h1v) << 16);
            agst32((char*)hp + (((size_t)(r0 + row)) * HH + colg) * 2, hu);    // h_t for S1(t+1)
            *(unsigned*)&myH[row][c2 * 2] = hu;                                // local copy for S2
        }
        rb_arrive(slots, cs, ep + 6); rb_wait(slots, ep + 6);
    }
}

// ---------------- host launcher ----------------
extern "C" void kernel_launch(void* const* d_in, const int* in_sizes, int n_in,
                              void* d_out, int out_size, void* d_ws, size_t ws_size,
                              hipStream_t stream)
{
    const float* x     = (const float*)d_in[0];   // (256,256,512)
    const float* Wih_w = (const float*)d_in[1];   // (512,2048)
    const float* Wih_b = (const float*)d_in[2];   // (2048)
    const float* Wmx_w = (const float*)d_in[3];   // (512,512)
    const float* Wmx_b = (const float*)d_in[4];   // (512)
    const float* Wmh_w = (const float*)d_in[5];   // (512,512)
    const float* Wmh_b = (const float*)d_in[6];   // (512)
    const float* Whm_w = (const float*)d_in[7];   // (512,2048)
    const float* Whm_b = (const float*)d_in[8];   // (2048)
    const float* Q     = (const float*)d_in[9];   // (512,512)
    const float* R     = (const float*)d_in[10];  // (512,512)
    float* out = (float*)d_out;                   // (256,256,512)

    char* ws = (char*)d_ws;
    ushort* QT   = (ushort*)ws;               ws += (size_t)512 * 512 * 2;   // bf16 [outcol][K]
    ushort* RT   = (ushort*)ws;               ws += (size_t)512 * 512 * 2;
    ushort* W1T  = (ushort*)ws;               ws += (size_t)G4  * 512 * 2;
    ushort* W2T  = (ushort*)ws;               ws += (size_t)G4  * 512 * 2;
    float*  biasg= (float*)ws;                ws += (size_t)G4 * 4;
    ushort* xa   = (ushort*)ws;               ws += (size_t)BB * HH * 2;
    ushort* hb1  = (ushort*)ws;               ws += (size_t)BB * HH * 2;
    ushort* xb   = (ushort*)ws;               ws += (size_t)BB * HH * 2;
    ushort* hb2  = (ushort*)ws;               ws += (size_t)BB * HH * 2;
    ushort* xc   = (ushort*)ws;               ws += (size_t)BB * HH * 2;
    ushort* hp   = (ushort*)ws;               ws += (size_t)BB * HH * 2;
    float*  Wtmp = (float*)ws;                ws += (size_t)512 * G4 * 4;    // prologue-only

    // Epoch slots alias post-prologue-dead Wtmp: 16 rb x 16 slots u32 = 1 KB.
    unsigned* flags = (unsigned*)Wtmp;

    // prologue: state init + weight prep
    init_state<<<512, 256, 0, stream>>>(hp);
    transpose_f32_bf16<<<dim3(16, 16), 256, 0, stream>>>(Q, QT, 512, 512);
    transpose_f32_bf16<<<dim3(16, 16), 256, 0, stream>>>(R, RT, 512, 512);
    combine_w<<<dim3(8, 64), 256, 0, stream>>>(Wih_w, Wmx_w, Whm_w, Wtmp, 1);   // W1 = Wih + Wmx@Whm
    transpose_f32_bf16<<<dim3(16, 64), 256, 0, stream>>>(Wtmp, W1T, 512, G4);
    combine_w<<<dim3(8, 64), 256, 0, stream>>>(nullptr, Wmh_w, Whm_w, Wtmp, 0); // W2 = Wmh@Whm
    transpose_f32_bf16<<<dim3(16, 64), 256, 0, stream>>>(Wtmp, W2T, 512, G4);
    bias_g_kernel<<<8, 256, 0, stream>>>(Wih_b, Whm_b, Wmx_b, Wmh_b, Whm_w, biasg);
    hipMemsetAsync(flags, 0, (size_t)16 * 16 * sizeof(unsigned), stream);

    // one persistent kernel for the entire sequence
    moglstm_persistent<<<256, 256, 0, stream>>>(x, QT, RT, W1T, W2T, biasg,
                                                hp, xa, hb1, xb, hb2, xc, out, flags);
}